// Round 1
// baseline (514.789 us; speedup 1.0000x reference)
//
#include <hip/hip_runtime.h>

#define BATCH 32
#define NODES 20000
#define FEAT  64
#define OUT   64
#define EIG   16

// ---- stage-1 chunking: grid (CHUNKS1, BATCH), block 256 ----
#define CHUNKS1 64
#define NPC1    313   // 64*313 = 20032 >= 20000
// ---- stage-3 chunking: grid (CHUNKS3, BATCH), block 256 ----
#define CHUNKS3 40
#define NPC3    500   // 40*500 = 20000 exactly

__global__ void k_zero(float* __restrict__ p, int n) {
    int idx = blockIdx.x * blockDim.x + threadIdx.x;
    if (idx < n) p[idx] = 0.0f;
}

// z[b,i,f] = sum_m V[m,f] * x[b,m,i]
// block: 256 threads = 4 node-lanes x 64 features(i). Each thread accumulates
// acc[16] over its node subset, LDS reduce across the 4 node-lanes, then
// 1024 fp32 atomicAdds per block into z (32 KiB total z, low contention).
__global__ void k_stage1(const float* __restrict__ x, const float* __restrict__ V,
                         float* __restrict__ z) {
    const int b = blockIdx.y;
    const int chunk = blockIdx.x;
    const int n0 = chunk * NPC1;
    const int n1 = (n0 + NPC1 < NODES) ? (n0 + NPC1) : NODES;
    const int t = threadIdx.x;
    const int i = t & 63;
    const int sub = t >> 6;   // 0..3

    float acc[EIG];
#pragma unroll
    for (int f = 0; f < EIG; f++) acc[f] = 0.0f;

    const float* xb = x + (size_t)b * NODES * FEAT;

    for (int m = n0 + sub; m < n1; m += 4) {
        const float xv = xb[(size_t)m * FEAT + i];          // coalesced: 64 lanes contiguous
        const float4* vp = (const float4*)(V + (size_t)m * EIG);  // wave-uniform broadcast
        const float4 v0 = vp[0], v1 = vp[1], v2 = vp[2], v3 = vp[3];
        acc[0]  += xv * v0.x;  acc[1]  += xv * v0.y;
        acc[2]  += xv * v0.z;  acc[3]  += xv * v0.w;
        acc[4]  += xv * v1.x;  acc[5]  += xv * v1.y;
        acc[6]  += xv * v1.z;  acc[7]  += xv * v1.w;
        acc[8]  += xv * v2.x;  acc[9]  += xv * v2.y;
        acc[10] += xv * v2.z;  acc[11] += xv * v2.w;
        acc[12] += xv * v3.x;  acc[13] += xv * v3.y;
        acc[14] += xv * v3.z;  acc[15] += xv * v3.w;
    }

    // LDS reduce across the 4 node-lanes (stride 17 to break bank aliasing)
    __shared__ float red[256][EIG + 1];
#pragma unroll
    for (int f = 0; f < EIG; f++) red[t][f] = acc[f];
    __syncthreads();

    if (sub == 0) {
        float* zb = z + ((size_t)b * FEAT + i) * EIG;
#pragma unroll
        for (int f = 0; f < EIG; f++) {
            float s = red[i][f] + red[i + 64][f] + red[i + 128][f] + red[i + 192][f];
            atomicAdd(&zb[f], s);
        }
    }
}

// w[b,j,e] = sum_{i,f} G[j,i,e,f] * z[b,i,f]
// grid (OUT, BATCH), block 64: thread t -> (e = t&15, i-slice s = t>>4).
__global__ void k_stage2(const float* __restrict__ G, const float* __restrict__ z,
                         float* __restrict__ w) {
    const int j = blockIdx.x;
    const int b = blockIdx.y;
    const int t = threadIdx.x;

    __shared__ float zs[FEAT * EIG];   // 4 KiB: z[b] staged once
    {
        const float4* zsrc = (const float4*)(z + (size_t)b * FEAT * EIG);
        float4* zdst = (float4*)zs;
#pragma unroll
        for (int k = t; k < FEAT * EIG / 4; k += 64) zdst[k] = zsrc[k];
    }
    __syncthreads();

    const int e = t & 15;
    const int s = t >> 4;   // 0..3 -> i in [16s, 16s+16)
    float acc = 0.0f;
    const float* Gj = G + (size_t)j * FEAT * EIG * EIG;

    for (int i = s * 16; i < s * 16 + 16; i++) {
        const float4* gp = (const float4*)(Gj + ((size_t)i * EIG + e) * EIG);
        const float4* zp = (const float4*)(zs + i * EIG);
        const float4 g0 = gp[0], g1 = gp[1], g2 = gp[2], g3 = gp[3];
        const float4 z0 = zp[0], z1 = zp[1], z2 = zp[2], z3 = zp[3];
        acc += g0.x * z0.x + g0.y * z0.y + g0.z * z0.z + g0.w * z0.w
             + g1.x * z1.x + g1.y * z1.y + g1.z * z1.z + g1.w * z1.w
             + g2.x * z2.x + g2.y * z2.y + g2.z * z2.z + g2.w * z2.w
             + g3.x * z3.x + g3.y * z3.y + g3.z * z3.z + g3.w * z3.w;
    }

    __shared__ float red[64];
    red[t] = acc;
    __syncthreads();
    if (s == 0)
        w[((size_t)b * OUT + j) * EIG + e] = red[e] + red[16 + e] + red[32 + e] + red[48 + e];
}

// out[b,n,j] = sum_e V[n,e] * w[b,j,e]
// block 256 = 4 node-lanes x 64 j; one wave handles one node -> 256 B coalesced store.
__global__ void k_stage3(const float* __restrict__ V, const float* __restrict__ w,
                         float* __restrict__ out) {
    const int b = blockIdx.y;
    const int chunk = blockIdx.x;
    const int t = threadIdx.x;
    const int j = t & 63;
    const int sub = t >> 6;

    const float4* wp = (const float4*)(w + ((size_t)b * OUT + j) * EIG);
    const float4 w0 = wp[0], w1 = wp[1], w2 = wp[2], w3 = wp[3];

    const int n0 = chunk * NPC3;
    float* ob = out + (size_t)b * NODES * OUT;

    for (int n = n0 + sub; n < n0 + NPC3; n += 4) {
        const float4* vp = (const float4*)(V + (size_t)n * EIG);   // wave-uniform broadcast
        const float4 v0 = vp[0], v1 = vp[1], v2 = vp[2], v3 = vp[3];
        float r = v0.x * w0.x + v0.y * w0.y + v0.z * w0.z + v0.w * w0.w
                + v1.x * w1.x + v1.y * w1.y + v1.z * w1.z + v1.w * w1.w
                + v2.x * w2.x + v2.y * w2.y + v2.z * w2.z + v2.w * w2.w
                + v3.x * w3.x + v3.y * w3.y + v3.z * w3.z + v3.w * w3.w;
        ob[(size_t)n * OUT + j] = r;
    }
}

extern "C" void kernel_launch(void* const* d_in, const int* in_sizes, int n_in,
                              void* d_out, int out_size, void* d_ws, size_t ws_size,
                              hipStream_t stream) {
    const float* x = (const float*)d_in[0];   // [32, 20000, 64]
    const float* V = (const float*)d_in[1];   // [20000, 16]
    const float* G = (const float*)d_in[2];   // [64, 64, 16, 16]
    float* out = (float*)d_out;               // [32, 20000, 64]

    float* z = (float*)d_ws;                          // [32, 64, 16] = 128 KiB
    float* w = z + (size_t)BATCH * FEAT * EIG;        // [32, 64, 16] = 128 KiB

    const int zn = BATCH * FEAT * EIG;  // 32768
    k_zero<<<(zn + 255) / 256, 256, 0, stream>>>(z, zn);

    k_stage1<<<dim3(CHUNKS1, BATCH), 256, 0, stream>>>(x, V, z);
    k_stage2<<<dim3(OUT, BATCH), 64, 0, stream>>>(G, z, w);
    k_stage3<<<dim3(CHUNKS3, BATCH), 256, 0, stream>>>(V, w, out);
}

// Round 2
// 350.100 us; speedup vs baseline: 1.4704x; 1.4704x over previous
//
#include <hip/hip_runtime.h>

#define BATCH 32
#define NODES 20000
#define FEAT  64
#define OUT   64
#define EIG   16

// stage-1/3 chunking: 256 nodes per block
#define NPC   256
#define CHUNKS 79   // 79*256 = 20224 >= 20000

__global__ void k_zero(float* __restrict__ p, int n) {
    int idx = blockIdx.x * blockDim.x + threadIdx.x;
    if (idx < n) p[idx] = 0.0f;
}

// z[b,i,f] = sum_m V[m,f] * x[b,m,i]
// Block 256 = 16 feature-groups (ig: features 4ig..4ig+3) x 16 m-subs.
// V chunk staged in LDS; x read as float4 (wave covers 1 KiB contiguous).
// Reduce: shfl across wave m-groups -> LDS across waves -> atomicAdd (79/addr).
__global__ void k_stage1(const float* __restrict__ x, const float* __restrict__ V,
                         float* __restrict__ z) {
    const int b = blockIdx.y;
    const int n0 = blockIdx.x * NPC;
    const int t = threadIdx.x;

    __shared__ float Vs[NPC * EIG];          // 16 KiB
    __shared__ float4 red4[64][EIG];         // 16 KiB (used after compute)

    {   // cooperative coalesced V stage (zero-pad past NODES)
        float4* vd = (float4*)Vs;
        const float4* vsrc = (const float4*)(V + (size_t)n0 * EIG);
        int avail = NODES - n0; if (avail > NPC) avail = NPC;
        const int avail4 = avail * EIG / 4;
#pragma unroll
        for (int k = t; k < NPC * EIG / 4; k += 256)
            vd[k] = (k < avail4) ? vsrc[k] : make_float4(0.f, 0.f, 0.f, 0.f);
    }
    __syncthreads();

    const int ig = t & 15;    // feature group
    const int ms = t >> 4;    // m-sub 0..15

    float4 acc[EIG];
#pragma unroll
    for (int f = 0; f < EIG; f++) acc[f] = make_float4(0.f, 0.f, 0.f, 0.f);

    const float* xb = x + (size_t)b * NODES * FEAT;

#pragma unroll
    for (int j = 0; j < NPC / 16; j++) {
        const int k = j * 16 + ms;
        if (n0 + k < NODES) {
            const float4 xv = *(const float4*)(xb + (size_t)(n0 + k) * FEAT + ig * 4);
            const float4* vr = (const float4*)(Vs + k * EIG);
            const float4 v0 = vr[0], v1 = vr[1], v2 = vr[2], v3 = vr[3];
            const float vf[EIG] = {v0.x,v0.y,v0.z,v0.w, v1.x,v1.y,v1.z,v1.w,
                                   v2.x,v2.y,v2.z,v2.w, v3.x,v3.y,v3.z,v3.w};
#pragma unroll
            for (int f = 0; f < EIG; f++) {
                acc[f].x += xv.x * vf[f];
                acc[f].y += xv.y * vf[f];
                acc[f].z += xv.z * vf[f];
                acc[f].w += xv.w * vf[f];
            }
        }
    }

    // intra-wave reduce across the 4 m-groups (lanes l, l+16, l+32, l+48)
#pragma unroll
    for (int f = 0; f < EIG; f++) {
        acc[f].x += __shfl_down(acc[f].x, 16); acc[f].x += __shfl_down(acc[f].x, 32);
        acc[f].y += __shfl_down(acc[f].y, 16); acc[f].y += __shfl_down(acc[f].y, 32);
        acc[f].z += __shfl_down(acc[f].z, 16); acc[f].z += __shfl_down(acc[f].z, 32);
        acc[f].w += __shfl_down(acc[f].w, 16); acc[f].w += __shfl_down(acc[f].w, 32);
    }

    const int wv = t >> 6;        // wave id 0..3
    const int l  = t & 63;        // lane
    if (l < 16) {
#pragma unroll
        for (int f = 0; f < EIG; f++) red4[wv * 16 + l][f] = acc[f];
    }
    __syncthreads();

    // phase 2: 1024 z-elements, 4 per thread; sum 4 waves, one atomic each
    const float* red = (const float*)red4;
    float* zb = z + (size_t)b * FEAT * EIG;
#pragma unroll
    for (int c2 = 0; c2 < 4; c2++) {
        const int p = t * 4 + c2;         // p = i*16 + f
        const int i = p >> 4, f = p & 15;
        const int igg = i >> 2, c = i & 3;
        float s = 0.f;
#pragma unroll
        for (int w = 0; w < 4; w++)
            s += red[((w * 16 + igg) * EIG + f) * 4 + c];
        atomicAdd(&zb[p], s);
    }
}

// w[b,j,e] = sum_{i,f} G[j,i,e,f] * z[b,i,f]   (tiny: 2048 single-wave blocks)
__global__ void k_stage2(const float* __restrict__ G, const float* __restrict__ z,
                         float* __restrict__ w) {
    const int j = blockIdx.x;
    const int b = blockIdx.y;
    const int t = threadIdx.x;

    __shared__ float zs[FEAT * EIG];
    {
        const float4* zsrc = (const float4*)(z + (size_t)b * FEAT * EIG);
        float4* zdst = (float4*)zs;
#pragma unroll
        for (int k = t; k < FEAT * EIG / 4; k += 64) zdst[k] = zsrc[k];
    }
    __syncthreads();

    const int e = t & 15;
    const int s = t >> 4;
    float acc = 0.0f;
    const float* Gj = G + (size_t)j * FEAT * EIG * EIG;

    for (int i = s * 16; i < s * 16 + 16; i++) {
        const float4* gp = (const float4*)(Gj + ((size_t)i * EIG + e) * EIG);
        const float4* zp = (const float4*)(zs + i * EIG);
        const float4 g0 = gp[0], g1 = gp[1], g2 = gp[2], g3 = gp[3];
        const float4 z0 = zp[0], z1 = zp[1], z2 = zp[2], z3 = zp[3];
        acc += g0.x * z0.x + g0.y * z0.y + g0.z * z0.z + g0.w * z0.w
             + g1.x * z1.x + g1.y * z1.y + g1.z * z1.z + g1.w * z1.w
             + g2.x * z2.x + g2.y * z2.y + g2.z * z2.z + g2.w * z2.w
             + g3.x * z3.x + g3.y * z3.y + g3.z * z3.z + g3.w * z3.w;
    }

    __shared__ float red[64];
    red[t] = acc;
    __syncthreads();
    if (s == 0)
        w[((size_t)b * OUT + j) * EIG + e] = red[e] + red[16 + e] + red[32 + e] + red[48 + e];
}

// out[b,n,j] = sum_e V[n,e] * w[b,j,e]
// V chunk in LDS (broadcast reads); w[b,j,:] in regs; 256 B coalesced stores.
__global__ void k_stage3(const float* __restrict__ V, const float* __restrict__ w,
                         float* __restrict__ out) {
    const int b = blockIdx.y;
    const int n0 = blockIdx.x * NPC;
    const int t = threadIdx.x;
    const int j = t & 63;
    const int wv = t >> 6;

    __shared__ float Vs[NPC * EIG];          // 16 KiB
    {
        float4* vd = (float4*)Vs;
        const float4* vsrc = (const float4*)(V + (size_t)n0 * EIG);
        int avail = NODES - n0; if (avail > NPC) avail = NPC;
        const int avail4 = avail * EIG / 4;
#pragma unroll
        for (int k = t; k < NPC * EIG / 4; k += 256)
            vd[k] = (k < avail4) ? vsrc[k] : make_float4(0.f, 0.f, 0.f, 0.f);
    }

    const float4* wp = (const float4*)(w + ((size_t)b * OUT + j) * EIG);
    const float4 w0 = wp[0], w1 = wp[1], w2 = wp[2], w3 = wp[3];
    __syncthreads();

    float* ob = out + (size_t)b * NODES * OUT;
    const int nEnd = (NODES - n0 < NPC) ? (NODES - n0) : NPC;

    for (int k = wv; k < nEnd; k += 4) {
        const float4* vr = (const float4*)(Vs + k * EIG);   // same addr all lanes: broadcast
        const float4 v0 = vr[0], v1 = vr[1], v2 = vr[2], v3 = vr[3];
        float r = v0.x * w0.x + v0.y * w0.y + v0.z * w0.z + v0.w * w0.w
                + v1.x * w1.x + v1.y * w1.y + v1.z * w1.z + v1.w * w1.w
                + v2.x * w2.x + v2.y * w2.y + v2.z * w2.z + v2.w * w2.w
                + v3.x * w3.x + v3.y * w3.y + v3.z * w3.z + v3.w * w3.w;
        ob[(size_t)(n0 + k) * OUT + j] = r;
    }
}

extern "C" void kernel_launch(void* const* d_in, const int* in_sizes, int n_in,
                              void* d_out, int out_size, void* d_ws, size_t ws_size,
                              hipStream_t stream) {
    const float* x = (const float*)d_in[0];   // [32, 20000, 64]
    const float* V = (const float*)d_in[1];   // [20000, 16]
    const float* G = (const float*)d_in[2];   // [64, 64, 16, 16]
    float* out = (float*)d_out;               // [32, 20000, 64]

    float* z = (float*)d_ws;                          // [32, 64, 16]
    float* w = z + (size_t)BATCH * FEAT * EIG;        // [32, 64, 16]

    const int zn = BATCH * FEAT * EIG;  // 32768
    k_zero<<<(zn + 255) / 256, 256, 0, stream>>>(z, zn);

    k_stage1<<<dim3(CHUNKS, BATCH), 256, 0, stream>>>(x, V, z);
    k_stage2<<<dim3(OUT, BATCH), 64, 0, stream>>>(G, z, w);
    k_stage3<<<dim3(CHUNKS, BATCH), 256, 0, stream>>>(V, w, out);
}